// Round 2
// baseline (219.805 us; speedup 1.0000x reference)
//
#include <hip/hip_runtime.h>

typedef __attribute__((ext_vector_type(8))) short short8;
typedef __attribute__((ext_vector_type(4))) float f32x4;

#define NLVL 8
#define C64 64

// ---- bf16 helpers (RNE) ----
__device__ __forceinline__ unsigned short f2bf(float f) {
    union { float f; unsigned u; } v; v.f = f;
    unsigned r = v.u + 0x7FFFu + ((v.u >> 16) & 1u);
    return (unsigned short)(r >> 16);
}
__device__ __forceinline__ float bf2f(unsigned short h) {
    union { unsigned u; float f; } v; v.u = ((unsigned)h) << 16;
    return v.f;
}

// ============================================================================
// Kernel 1: convert W_lvl (510, 2, 64, 64) f32  ->  Wt (510, 64, 256) bf16
// Wt[kf][d][kin2]:  kin2 = h*128 + (s*64 + c), h=0 -> hi bf16, h=1 -> lo bf16
// (hi/lo split kills weight-quantization error; A fragments are reused for
//  both halves so activation traffic is unchanged.)
// ============================================================================
__global__ __launch_bounds__(256) void k_convw(const float* __restrict__ W_lvl,
                                               unsigned short* __restrict__ Wt) {
    __shared__ float buf[128 * 65];   // padded transpose buffer
    const int kf = blockIdx.x;
    const int i  = threadIdx.x;
    const float* src = W_lvl + (size_t)kf * 8192;
    for (int m = 0; m < 32; ++m) {
        int idx = m * 256 + i;          // 0..8191, flat [kin][d]
        int kin = idx >> 6, d = idx & 63;
        buf[kin * 65 + d] = src[idx];
    }
    __syncthreads();
    unsigned short* dst = Wt + (size_t)kf * 16384;
    for (int m = 0; m < 64; ++m) {
        int o = m * 256 + i;            // 0..16383, flat [d][kin2]
        int d = o >> 8;
        int kin2 = o & 255;
        int kin = kin2 & 127;
        float val = buf[kin * 65 + d];
        unsigned short hi = f2bf(val);
        unsigned short outv = (kin2 >> 7) ? f2bf(val - bf2f(hi)) : hi;
        dst[o] = outv;
    }
}

// ============================================================================
// Kernel 2: level-0 input projection.  x(B,256,16) @ W_in(16,64) + b_in, relu
//   -> V0 bf16, layout [b][256][64]  (rows = b*256 + kblk)
// ============================================================================
__global__ __launch_bounds__(256) void k_lvl0(const float* __restrict__ x,
                                              const float* __restrict__ W_in,
                                              const float* __restrict__ b_in,
                                              unsigned short* __restrict__ V0) {
    __shared__ float wl[16 * 64];
    __shared__ float bl[64];
    __shared__ float xl[16 * 16];
    const int i = threadIdx.x;
    for (int m = 0; m < 4; ++m) wl[m * 256 + i] = W_in[m * 256 + i];
    if (i < 64) bl[i] = b_in[i];
    const int row0 = blockIdx.x * 16;                 // 16 rows per block
    xl[i] = x[(size_t)row0 * 16 + i];                 // contiguous
    __syncthreads();
    const int r  = i >> 4;
    const int c0 = (i & 15) * 4;
    float a0 = bl[c0], a1 = bl[c0 + 1], a2 = bl[c0 + 2], a3 = bl[c0 + 3];
#pragma unroll
    for (int f = 0; f < 16; ++f) {
        float xv = xl[r * 16 + f];
        const float* wrow = &wl[f * 64 + c0];
        a0 += xv * wrow[0]; a1 += xv * wrow[1]; a2 += xv * wrow[2]; a3 += xv * wrow[3];
    }
    size_t ob = (size_t)(row0 + r) * 64 + c0;
    V0[ob]     = f2bf(fmaxf(a0, 0.f));
    V0[ob + 1] = f2bf(fmaxf(a1, 0.f));
    V0[ob + 2] = f2bf(fmaxf(a2, 0.f));
    V0[ob + 3] = f2bf(fmaxf(a3, 0.f));
}

// ============================================================================
// Kernel 3: one butterfly level (lvl = 1..8).
//  Block: sibling pair (children 2p, 2p+1) x 64-row M tile. 4 waves.
//  W (both children, hi/lo) staged in 64 KB LDS with XOR-chunk swizzle.
//  A fragments loaded straight global->VGPR (each element used once per block).
//  mfma_f32_16x16x32_bf16; K-loop of 8 (hi then lo halves reuse a[kk&3]).
// ============================================================================
__global__ __launch_bounds__(256) void k_level(const unsigned short* __restrict__ Vprev,
                                               unsigned short* __restrict__ Vnext,
                                               const unsigned short* __restrict__ Wt,
                                               const float* __restrict__ b_lvl,
                                               int lvl) {
    extern __shared__ unsigned short wlds[];          // 32768 ushorts = 64 KB
    const int T   = 1 << (8 - lvl);
    const int lgT = 8 - lvl;
    const int off = (1 << lvl) - 2;
    const int parent = blockIdx.y;
    const int tid = threadIdx.x;

    // ---- stage both children's weights, swizzled (chunk ^= d&7) ----
    {
        const uint4* gsrc = (const uint4*)(Wt + (size_t)(off + 2 * parent) * 16384);
        uint4* ldst = (uint4*)wlds;
#pragma unroll
        for (int m = 0; m < 16; ++m) {
            int p = m * 256 + tid;                    // chunk id 0..4095
            uint4 v = gsrc[p];
            int sw = p ^ ((p >> 5) & 7);              // d = (p>>5)&63; XOR low3
            ldst[sw] = v;
        }
    }
    __syncthreads();

    const int w  = tid >> 6;                          // wave 0..3
    const int l  = tid & 63;
    const int q  = l >> 4;                            // 0..3
    const int ln = l & 15;

    // ---- A fragments: row = tile row (l&15), k = q*8 + j (+32*kk) ----
    const int r_global = blockIdx.x * 64 + w * 16 + ln;
    const int b  = r_global >> lgT;
    const int t  = r_global & (T - 1);
    const unsigned short* Abase =
        Vprev + ((size_t)b << 14) + (size_t)parent * ((size_t)T << 7) + (size_t)t * 128 + q * 8;

    short8 a[4];
#pragma unroll
    for (int kk = 0; kk < 4; ++kk)
        a[kk] = *(const short8*)(Abase + kk * 32);

    f32x4 acc[2][4];
    f32x4 zero = {0.f, 0.f, 0.f, 0.f};
#pragma unroll
    for (int s = 0; s < 2; ++s)
#pragma unroll
        for (int nt = 0; nt < 4; ++nt) acc[s][nt] = zero;

#pragma unroll
    for (int s = 0; s < 2; ++s) {
#pragma unroll
        for (int nt = 0; nt < 4; ++nt) {
            const int d = nt * 16 + ln;
#pragma unroll
            for (int kk = 0; kk < 8; ++kk) {
                int ch = (s << 11) + (d << 5) + (kk << 2) + q;  // logical chunk
                ch ^= (d & 7);                                   // swizzle
                short8 bfrag = *(const short8*)((const unsigned short*)wlds + ch * 8);
                acc[s][nt] = __builtin_amdgcn_mfma_f32_16x16x32_bf16(
                    a[kk & 3], bfrag, acc[s][nt], 0, 0, 0);
            }
        }
    }

    // ---- epilogue: bias + relu + bf16 store ----
#pragma unroll
    for (int s = 0; s < 2; ++s) {
        const int kf_local = 2 * parent + s;
        const float* brow = b_lvl + (size_t)(off + kf_local) * 64;
#pragma unroll
        for (int nt = 0; nt < 4; ++nt) {
            float bias = brow[nt * 16 + ln];
#pragma unroll
            for (int j = 0; j < 4; ++j) {
                int rl = w * 16 + q * 4 + j;
                int rg = blockIdx.x * 64 + rl;
                int bb = rg >> lgT;
                int tt = rg & (T - 1);
                float v = fmaxf(acc[s][nt][j] + bias, 0.f);
                Vnext[((size_t)bb << 14) + (size_t)kf_local * ((size_t)T << 6) +
                      (size_t)tt * 64 + nt * 16 + ln] = f2bf(v);
            }
        }
    }
}

// ============================================================================
// Kernel 4: output projection  out[b,k,f] = sum_c V8[b,k,c] * Fea[k,c,f]
// ============================================================================
__global__ __launch_bounds__(256) void k_final(const unsigned short* __restrict__ V8,
                                               const float* __restrict__ Fea,
                                               float* __restrict__ out) {
    __shared__ float fl[64 * 16];
    __shared__ unsigned short vl[16 * 64];
    const int k  = blockIdx.x;                        // 0..255
    const int b0 = blockIdx.y * 16;
    const int i  = threadIdx.x;
    for (int m = 0; m < 4; ++m) fl[m * 256 + i] = Fea[(size_t)k * 1024 + m * 256 + i];
    {
        int idx = i * 4;                              // 0..1023
        int bl2 = idx >> 6, c = idx & 63;
        const unsigned short* src = V8 + ((size_t)(b0 + bl2) << 14) + k * 64 + c;
        *(uint2*)&vl[idx] = *(const uint2*)src;
    }
    __syncthreads();
    const int bl2 = i >> 4, f = i & 15;
    float acc = 0.f;
#pragma unroll
    for (int c = 0; c < 64; ++c)
        acc += bf2f(vl[bl2 * 64 + c]) * fl[c * 16 + f];
    out[(size_t)(b0 + bl2) * 4096 + (size_t)k * 16 + f] = acc;
}

// ============================================================================
extern "C" void kernel_launch(void* const* d_in, const int* in_sizes, int n_in,
                              void* d_out, int out_size, void* d_ws, size_t ws_size,
                              hipStream_t stream) {
    const float* in_data = (const float*)d_in[0];
    const float* W_in    = (const float*)d_in[1];
    const float* b_in    = (const float*)d_in[2];
    const float* W_lvl   = (const float*)d_in[3];
    const float* b_lvl   = (const float*)d_in[4];
    const float* Fea     = (const float*)d_in[5];
    float* out = (float*)d_out;

    // workspace layout: Wt bf16 (16,711,680 B) | V0 (16,777,216 B) | V1 (16,777,216 B)
    unsigned short* Wt = (unsigned short*)d_ws;
    unsigned short* Va = (unsigned short*)((char*)d_ws + 16711680);
    unsigned short* Vb = (unsigned short*)((char*)d_ws + 16711680 + 16777216);

    k_convw<<<510, 256, 0, stream>>>(W_lvl, Wt);
    k_lvl0<<<8192, 256, 0, stream>>>(in_data, W_in, b_in, Va);

    const unsigned short* cur = Va;
    unsigned short* nxt = Vb;
    for (int lvl = 1; lvl <= NLVL; ++lvl) {
        int T = 1 << (8 - lvl);
        dim3 grid(8 * T, 1 << (lvl - 1));
        k_level<<<grid, 256, 65536, stream>>>(cur, nxt, Wt, b_lvl, lvl);
        unsigned short* tmp = (unsigned short*)cur;
        cur = nxt;
        nxt = tmp;
    }
    k_final<<<dim3(256, 32), 256, 0, stream>>>(cur, Fea, out);
}